// Round 9
// baseline (4848.243 us; speedup 1.0000x reference)
//
#include <hip/hip_runtime.h>
#include <math.h>

#define NN 100000
#define NE 1600000
#define NP 500000
#define KHOPS 6
#define ECHK 50000          // edge chunk rows; o1 [ECHK,512] bf16 = 51.2 MB = outT
#define NB_SCAN ((NN + 1023) / 1024)

typedef unsigned short u16;
typedef short bf16x8 __attribute__((ext_vector_type(8)));
typedef float f32x4 __attribute__((ext_vector_type(4)));

__device__ __forceinline__ float gelu_erf(float x) {
    return 0.5f * x * (1.0f + erff(x * 0.70710678118654752f));
}
__device__ __forceinline__ float b2f(u16 u) {
    return __uint_as_float(((unsigned int)u) << 16);
}
__device__ __forceinline__ u16 f2b(float f) {
    unsigned int x = __float_as_uint(f);
    return (u16)((x + 0x7FFFu + ((x >> 16) & 1u)) >> 16);
}
__device__ __forceinline__ bf16x8 cvt8(float4 a, float4 b) {
    bf16x8 v;
    v[0]=(short)f2b(a.x); v[1]=(short)f2b(a.y); v[2]=(short)f2b(a.z); v[3]=(short)f2b(a.w);
    v[4]=(short)f2b(b.x); v[5]=(short)f2b(b.y); v[6]=(short)f2b(b.z); v[7]=(short)f2b(b.w);
    return v;
}

// ---------------- column statistics
template<int BF>
__global__ void col_stats(const void* __restrict__ Matv, int rows, int lc,
                          const int* __restrict__ w0, const int* __restrict__ w1,
                          float* __restrict__ sums, float* __restrict__ sumsq,
                          int base0, int base1)
{
    __shared__ float red[256];
    const int t = threadIdx.x;
    const int C = 1 << lc;
    const long total = (long)rows << lc;
    const long stride = (long)gridDim.x * 256;
    float s0 = 0.f, q0 = 0.f, s1 = 0.f, q1 = 0.f;
    for (long idx = (long)blockIdx.x * 256 + t; idx < total; idx += stride) {
        int r = (int)(idx >> lc);
        float v = BF ? b2f(((const u16*)Matv)[idx]) : ((const float*)Matv)[idx];
        float f0 = w0 ? (float)w0[r] : 1.0f;
        s0 += f0 * v;
        q0 += f0 * v * v;
        if (w1) {
            float f1 = (float)w1[r];
            s1 += f1 * v;
            q1 += f1 * v * v;
        }
    }
    red[t] = s0; __syncthreads();
    if (t < C) { float x = 0.f; for (int k = t; k < 256; k += C) x += red[k]; atomicAdd(&sums[base0 + t], x); }
    __syncthreads();
    red[t] = q0; __syncthreads();
    if (t < C) { float x = 0.f; for (int k = t; k < 256; k += C) x += red[k]; atomicAdd(&sumsq[base0 + t], x); }
    __syncthreads();
    if (w1) {
        red[t] = s1; __syncthreads();
        if (t < C) { float x = 0.f; for (int k = t; k < 256; k += C) x += red[k]; atomicAdd(&sums[base1 + t], x); }
        __syncthreads();
        red[t] = q1; __syncthreads();
        if (t < C) { float x = 0.f; for (int k = t; k < 256; k += C) x += red[k]; atomicAdd(&sumsq[base1 + t], x); }
    }
}

__global__ void bn_finalize(const float* __restrict__ sums, const float* __restrict__ sumsq,
                            const float* __restrict__ g, const float* __restrict__ b,
                            float* __restrict__ s, float* __restrict__ t,
                            int C, float count, float eps)
{
    int c = blockIdx.x * blockDim.x + threadIdx.x;
    if (c < C) {
        float mu = sums[c] / count;
        float var = sumsq[c] / count - mu * mu;
        float sc = g[c] * rsqrtf(var + eps);
        s[c] = sc;
        t[c] = b[c] - mu * sc;
    }
}

__global__ void hist_add(const int* __restrict__ idx, int n, int* __restrict__ cnt)
{
    int stride = gridDim.x * blockDim.x;
    for (int i = blockIdx.x * blockDim.x + threadIdx.x; i < n; i += stride)
        atomicAdd(&cnt[idx[i]], 1);
}

__global__ void hist_add2(const int* __restrict__ i0, const int* __restrict__ i1, int n,
                          int* __restrict__ c0, int* __restrict__ c1)
{
    int stride = gridDim.x * blockDim.x;
    for (int i = blockIdx.x * blockDim.x + threadIdx.x; i < n; i += stride) {
        atomicAdd(&c0[i0[i]], 1);
        atomicAdd(&c1[i1[i]], 1);
    }
}

__global__ void scan1(const int* __restrict__ cnt, int* __restrict__ ex,
                      int* __restrict__ part, int n)
{
    __shared__ int buf[1024];
    int b = blockIdx.x, t = threadIdx.x;
    int i = b * 1024 + t;
    int v = (i < n) ? cnt[i] : 0;
    buf[t] = v;
    __syncthreads();
    int incl = v;
    for (int o = 1; o < 1024; o <<= 1) {
        int tmp = (t >= o) ? buf[t - o] : 0;
        __syncthreads();
        incl += tmp;
        buf[t] = incl;
        __syncthreads();
    }
    if (i < n) ex[i] = incl - v;
    if (t == 1023) part[b] = incl;
}

__global__ void scan2(int* __restrict__ part, int nb)
{
    __shared__ int s[256];
    int t = threadIdx.x;
    if (t < nb) s[t] = part[t];
    __syncthreads();
    if (t == 0) {
        int run = 0;
        for (int b = 0; b < nb; ++b) { int x = s[b]; part[b] = run; run += x; }
        part[nb] = run;
    }
}

__global__ void scan3(int* __restrict__ indptr, const int* __restrict__ part,
                      const int* __restrict__ cnt, float* __restrict__ dinv, int n)
{
    int b = blockIdx.x, t = threadIdx.x;
    int i = b * 1024 + t;
    if (i < n) {
        indptr[i] += part[b];
        int c = cnt[i];
        dinv[i] = (c > 0) ? rsqrtf((float)c) : 0.f;
    }
    if (b == 0 && t == 0) indptr[n] = part[NB_SCAN];
}

__global__ void csr_build(const int* __restrict__ src, const int* __restrict__ dst, int n,
                          const int* __restrict__ indptr, int* __restrict__ cursor,
                          int* __restrict__ csrS)
{
    int stride = gridDim.x * blockDim.x;
    for (int e = blockIdx.x * blockDim.x + threadIdx.x; e < n; e += stride) {
        int s = src[e], d = dst[e];
        int pos = indptr[d] + atomicAdd(&cursor[d], 1);
        csrS[pos] = s;
    }
}

// hout[n, 2l..2l+1] via ushort2; 8-edge unroll
__global__ void spmm_hop(const u16* __restrict__ hin, u16* __restrict__ hout,
                         const int* __restrict__ indptr, const int* __restrict__ csrS,
                         const float* __restrict__ dinv)
{
    int gid = blockIdx.x * blockDim.x + threadIdx.x;
    int node = gid >> 6;
    int lane = gid & 63;
    if (node >= NN) return;
    float dn = dinv[node];
    int beg = indptr[node], end = indptr[node + 1];
    float a0 = 0.f, a1 = 0.f;
    int e = beg;
    for (; e + 7 < end; e += 8) {
        int sidx[8];
        ushort2 pv[8];
#pragma unroll
        for (int u = 0; u < 8; ++u) sidx[u] = csrS[e + u];
#pragma unroll
        for (int u = 0; u < 8; ++u)
            pv[u] = *(const ushort2*)(hin + (size_t)sidx[u] * 128 + lane * 2);
#pragma unroll
        for (int u = 0; u < 8; ++u) {
            float wv = dn * dinv[sidx[u]];
            a0 = fmaf(wv, b2f(pv[u].x), a0);
            a1 = fmaf(wv, b2f(pv[u].y), a1);
        }
    }
    for (; e < end; ++e) {
        int s0 = csrS[e];
        float w0 = dn * dinv[s0];
        ushort2 p0 = *(const ushort2*)(hin + (size_t)s0 * 128 + lane * 2);
        a0 = fmaf(w0, b2f(p0.x), a0);
        a1 = fmaf(w0, b2f(p0.y), a1);
    }
    ushort2 o;
    o.x = f2b(a0); o.y = f2b(a1);
    *(ushort2*)(hout + (size_t)node * 128 + lane * 2) = o;
}

__global__ void convTB(const float* __restrict__ in, u16* __restrict__ out,
                       int K, int Nc, int B)
{
    int per = K * Nc;
    int i = blockIdx.x * blockDim.x + threadIdx.x;
    if (i < per * B) {
        int m = i / per, r = i - m * per;
        int n = r / K, k = r - n * K;
        out[i] = f2b(in[(size_t)m * per + (size_t)k * Nc + n]);
    }
}

// stacked TAG pair weights: out[p][n][k(0..255)] = bf16(Ws[2p + (k>=128)][k&127][n])
__global__ void conv_pair(const float* __restrict__ Ws, u16* __restrict__ out)
{
    int i = blockIdx.x * blockDim.x + threadIdx.x;
    if (i < 3 * 128 * 256) {
        int p = i >> 15;
        int r = i & 32767;
        int n = r >> 8, k = r & 255;
        int hop = 2 * p + (k >> 7);
        out[i] = f2b(Ws[(size_t)hop * 16384 + (size_t)(k & 127) * 128 + n]);
    }
}

// plain fp32 -> bf16 convert, float4-vectorized
__global__ void convB(const float* __restrict__ in, u16* __restrict__ out, int n4)
{
    int stride = gridDim.x * blockDim.x;
    for (int i = blockIdx.x * blockDim.x + threadIdx.x; i < n4; i += stride) {
        float4 v = ((const float4*)in)[i];
        ushort4 o;
        o.x = f2b(v.x); o.y = f2b(v.y); o.z = f2b(v.z); o.w = f2b(v.w);
        ((ushort4*)out)[i] = o;
    }
}

__global__ void fold_wT(const float* __restrict__ W0, const float* __restrict__ s,
                        u16* __restrict__ out)
{
    int i = blockIdx.x * blockDim.x + threadIdx.x;
    if (i < 512 * 544) {
        int n = i / 544, k = i - n * 544;
        out[i] = f2b(s[k] * W0[(size_t)k * 512 + n]);
    }
}

__global__ void fold_b(const float* __restrict__ W0, const float* __restrict__ b0,
                       const float* __restrict__ tv, float* __restrict__ bp)
{
    int j = blockIdx.x * blockDim.x + threadIdx.x;
    if (j < 512) {
        float s = b0[j];
        for (int k = 0; k < 544; ++k) s = fmaf(tv[k], W0[k * 512 + j], s);
        bp[j] = s;
    }
}

// ---- shared A-tile loader ----
// AMODE 0: dense bf16 A0, lda
// AMODE 1: concat [BN(fp32 A0, sv/tv) | bf16 A1], stride 128, Kd=256
// AMODE 2: edge gather [aEmb[i0]|aEmb[i1]|Xb[i0]|Xb[i1]|bf16(Y)], Kd=544
// AMODE 3: BN-on-the-fly fp32 A0, stride 128
// AMODE 5: concat [bf16 A0 | bf16 A1], stride 128, Kd=256
template<int AMODE>
__device__ __forceinline__ bf16x8 load_a_slot(
    const void* __restrict__ A0v, const void* __restrict__ A1v,
    const float* __restrict__ Yp, const int* __restrict__ i0s, const int* __restrict__ i1s,
    int rowOffset, const float* __restrict__ sv, const float* __restrict__ tv,
    int row, int r, int k0, int sl, int Mr, int lda)
{
    bf16x8 val = {0, 0, 0, 0, 0, 0, 0, 0};
    if (row < Mr) {
        if (AMODE == 0) {
            val = *(const bf16x8*)((const u16*)A0v + (size_t)row * lda + k0 + sl * 8);
        } else if (AMODE == 5) {
            int c = k0 + sl * 8;
            const u16* Ap = (c < 128) ? (const u16*)A0v : (const u16*)A1v;
            val = *(const bf16x8*)(Ap + (size_t)row * 128 + (c & 127));
        } else if (AMODE == 1) {
            int c = k0 + sl * 8;
            if (c < 128) {
                const float* xp = (const float*)A0v + (size_t)row * 128 + c;
                float4 x0 = *(const float4*)xp, x1 = *(const float4*)(xp + 4);
                float4 s0 = *(const float4*)(sv + c), s1 = *(const float4*)(sv + c + 4);
                float4 t0 = *(const float4*)(tv + c), t1 = *(const float4*)(tv + c + 4);
                float4 a = make_float4(fmaf(x0.x,s0.x,t0.x), fmaf(x0.y,s0.y,t0.y),
                                       fmaf(x0.z,s0.z,t0.z), fmaf(x0.w,s0.w,t0.w));
                float4 b = make_float4(fmaf(x1.x,s1.x,t1.x), fmaf(x1.y,s1.y,t1.y),
                                       fmaf(x1.z,s1.z,t1.z), fmaf(x1.w,s1.w,t1.w));
                val = cvt8(a, b);
            } else {
                val = *(const bf16x8*)((const u16*)A1v + (size_t)row * 128 + (c - 128));
            }
        } else if (AMODE == 3) {
            int c = k0 + sl * 8;
            const float* xp = (const float*)A0v + (size_t)row * 128 + c;
            float4 x0 = *(const float4*)xp, x1 = *(const float4*)(xp + 4);
            float4 s0 = *(const float4*)(sv + c), s1 = *(const float4*)(sv + c + 4);
            float4 t0 = *(const float4*)(tv + c), t1 = *(const float4*)(tv + c + 4);
            float4 a = make_float4(fmaf(x0.x,s0.x,t0.x), fmaf(x0.y,s0.y,t0.y),
                                   fmaf(x0.z,s0.z,t0.z), fmaf(x0.w,s0.w,t0.w));
            float4 b = make_float4(fmaf(x1.x,s1.x,t1.x), fmaf(x1.y,s1.y,t1.y),
                                   fmaf(x1.z,s1.z,t1.z), fmaf(x1.w,s1.w,t1.w));
            val = cvt8(a, b);
        } else { // AMODE 2
            int seg = k0 >> 7;
            int c = (k0 & 127) + sl * 8;
            if (seg == 0) {
                val = *(const bf16x8*)((const u16*)A0v + (size_t)i0s[r] * 128 + c);
            } else if (seg == 1) {
                val = *(const bf16x8*)((const u16*)A0v + (size_t)i1s[r] * 128 + c);
            } else if (seg == 2) {
                val = *(const bf16x8*)((const u16*)A1v + (size_t)i0s[r] * 128 + c);
            } else if (seg == 3) {
                val = *(const bf16x8*)((const u16*)A1v + (size_t)i1s[r] * 128 + c);
            } else {
                const float* yp = Yp + (size_t)(rowOffset + row) * 32 + sl * 8;
                val = cvt8(*(const float4*)yp, *(const float4*)(yp + 4));
            }
        }
    }
    return val;
}

// ------------- 4-wave MFMA GEMM: tile 128x128, BK=32
template<int AMODE, int ACT, int ACCUM, int OUTBF>
__launch_bounds__(256, 2)
__global__ void gemm_mfma(const void* __restrict__ A0v, const void* __restrict__ A1v,
                          const float* __restrict__ Yp,
                          const int* __restrict__ I0, const int* __restrict__ I1,
                          int rowOffset,
                          const float* __restrict__ sv, const float* __restrict__ tv,
                          const u16* __restrict__ Wb, const float* __restrict__ bias,
                          void* __restrict__ Cv, const float* __restrict__ Cacc,
                          int Mr, int Kd, int Nc, int lda)
{
    __shared__ __align__(16) u16 As[128 * 32];
    __shared__ __align__(16) u16 Bs[128 * 32];
    __shared__ int i0s[128], i1s[128];

    const int t = threadIdx.x;
    const int lane = t & 63;
    const int wid = t >> 6;
    const int wm = wid >> 1, wn = wid & 1;
    const int lb = lane & 15, lh = lane >> 4;
    const int row0 = blockIdx.x * 128;
    const int colb = blockIdx.y * 128;

    if (AMODE == 2) {
        if (t < 128) {
            int r = row0 + t;
            i0s[t] = (r < Mr) ? I0[rowOffset + r] : 0;
        } else {
            int r = row0 + (t - 128);
            i1s[t - 128] = (r < Mr) ? I1[rowOffset + r] : 0;
        }
    }

    f32x4 acc[4][4];
#pragma unroll
    for (int i = 0; i < 4; ++i)
#pragma unroll
        for (int j = 0; j < 4; ++j) acc[i][j] = (f32x4){0.f, 0.f, 0.f, 0.f};

    for (int k0 = 0; k0 < Kd; k0 += 32) {
        __syncthreads();
#pragma unroll
        for (int h = 0; h < 2; ++h) {
            int s = t + h * 256;
            int r = s >> 2, sl = s & 3;
            bf16x8 val = load_a_slot<AMODE>(A0v, A1v, Yp, i0s, i1s, rowOffset, sv, tv,
                                            row0 + r, r, k0, sl, Mr, lda);
            *(bf16x8*)&As[r * 32 + ((sl ^ ((r >> 1) & 3)) << 3)] = val;
        }
#pragma unroll
        for (int h = 0; h < 2; ++h) {
            int s = t + h * 256;
            int n = s >> 2, sl = s & 3;
            bf16x8 val = *(const bf16x8*)(Wb + (size_t)(colb + n) * Kd + k0 + sl * 8);
            *(bf16x8*)&Bs[n * 32 + ((sl ^ ((n >> 1) & 3)) << 3)] = val;
        }
        __syncthreads();
        bf16x8 af[4], bfr[4];
#pragma unroll
        for (int i = 0; i < 4; ++i) {
            int r = wm * 64 + i * 16 + lb;
            af[i] = *(const bf16x8*)&As[r * 32 + ((lh ^ ((r >> 1) & 3)) << 3)];
        }
#pragma unroll
        for (int j = 0; j < 4; ++j) {
            int n = wn * 64 + j * 16 + lb;
            bfr[j] = *(const bf16x8*)&Bs[n * 32 + ((lh ^ ((n >> 1) & 3)) << 3)];
        }
#pragma unroll
        for (int i = 0; i < 4; ++i)
#pragma unroll
            for (int j = 0; j < 4; ++j)
                acc[i][j] = __builtin_amdgcn_mfma_f32_16x16x32_bf16(af[i], bfr[j], acc[i][j], 0, 0, 0);
    }

#pragma unroll
    for (int i = 0; i < 4; ++i) {
#pragma unroll
        for (int j = 0; j < 4; ++j) {
            int col = colb + wn * 64 + j * 16 + lb;
#pragma unroll
            for (int r = 0; r < 4; ++r) {
                int row = row0 + wm * 64 + i * 16 + lh * 4 + r;
                if (row < Mr) {
                    size_t off = (size_t)row * Nc + col;
                    float v = acc[i][j][r];
                    if (ACCUM) v += Cacc[off];
                    if (ACT) v = gelu_erf(v + bias[col]);
                    if (OUTBF) ((u16*)Cv)[off] = f2b(v);
                    else       ((float*)Cv)[off] = v;
                }
            }
        }
    }
}

// ------------- 8-wave MFMA GEMM: tile 128xNCOLS (256 or 512), BK=32
template<int AMODE, int ACT, int OUTBF, int NCOLS>
__launch_bounds__(512, 4)
__global__ void gemm_wide(const void* __restrict__ A0v, const void* __restrict__ A1v,
                          const float* __restrict__ Yp,
                          const int* __restrict__ I0, const int* __restrict__ I1,
                          int rowOffset,
                          const float* __restrict__ sv, const float* __restrict__ tv,
                          const u16* __restrict__ Wb, const float* __restrict__ bias,
                          void* __restrict__ Cv, int Mr, int Kd, int Nc)
{
    constexpr int NJ = NCOLS / 64;      // col frags per wave
    constexpr int WCOL = NCOLS / 4;     // cols per wave
    constexpr int BH = NCOLS / 128;     // B-staging iters per thread

    __shared__ __align__(16) u16 As[128 * 32];
    __shared__ __align__(16) u16 Bs[NCOLS * 32];
    __shared__ int i0s[128], i1s[128];

    const int t = threadIdx.x;
    const int lane = t & 63;
    const int wid = t >> 6;
    const int wm = wid >> 2, wn = wid & 3;
    const int lb = lane & 15, lh = lane >> 4;
    const int row0 = blockIdx.x * 128;
    const int colb = blockIdx.y * NCOLS;

    if (AMODE == 2) {
        if (t < 128) {
            int r = row0 + t;
            i0s[t] = (r < Mr) ? I0[rowOffset + r] : 0;
        } else if (t < 256) {
            int r = row0 + (t - 128);
            i1s[t - 128] = (r < Mr) ? I1[rowOffset + r] : 0;
        }
    }

    f32x4 acc[4][NJ];
#pragma unroll
    for (int i = 0; i < 4; ++i)
#pragma unroll
        for (int j = 0; j < NJ; ++j) acc[i][j] = (f32x4){0.f, 0.f, 0.f, 0.f};

    for (int k0 = 0; k0 < Kd; k0 += 32) {
        __syncthreads();
        {
            int r = t >> 2, sl = t & 3;
            bf16x8 val = load_a_slot<AMODE>(A0v, A1v, Yp, i0s, i1s, rowOffset, sv, tv,
                                            row0 + r, r, k0, sl, Mr, 0);
            *(bf16x8*)&As[r * 32 + ((sl ^ ((r >> 1) & 3)) << 3)] = val;
        }
#pragma unroll
        for (int h = 0; h < BH; ++h) {
            int s = t + h * 512;
            int n = s >> 2, sl = s & 3;
            bf16x8 val = *(const bf16x8*)(Wb + (size_t)(colb + n) * Kd + k0 + sl * 8);
            *(bf16x8*)&Bs[n * 32 + ((sl ^ ((n >> 1) & 3)) << 3)] = val;
        }
        __syncthreads();
        bf16x8 af[4], bfr[NJ];
#pragma unroll
        for (int i = 0; i < 4; ++i) {
            int r = wm * 64 + i * 16 + lb;
            af[i] = *(const bf16x8*)&As[r * 32 + ((lh ^ ((r >> 1) & 3)) << 3)];
        }
#pragma unroll
        for (int j = 0; j < NJ; ++j) {
            int n = wn * WCOL + j * 16 + lb;
            bfr[j] = *(const bf16x8*)&Bs[n * 32 + ((lh ^ ((n >> 1) & 3)) << 3)];
        }
#pragma unroll
        for (int i = 0; i < 4; ++i)
#pragma unroll
            for (int j = 0; j < NJ; ++j)
                acc[i][j] = __builtin_amdgcn_mfma_f32_16x16x32_bf16(af[i], bfr[j], acc[i][j], 0, 0, 0);
    }

#pragma unroll
    for (int i = 0; i < 4; ++i) {
#pragma unroll
        for (int j = 0; j < NJ; ++j) {
            int col = colb + wn * WCOL + j * 16 + lb;
#pragma unroll
            for (int r = 0; r < 4; ++r) {
                int row = row0 + wm * 64 + i * 16 + lh * 4 + r;
                if (row < Mr) {
                    size_t off = (size_t)row * Nc + col;
                    float v = acc[i][j][r];
                    if (ACT) v = gelu_erf(v + bias[col]);
                    if (OUTBF) ((u16*)Cv)[off] = f2b(v);
                    else       ((float*)Cv)[off] = v;
                }
            }
        }
    }
}

// ------------- edge layer-2 + sigmoid head fused
__launch_bounds__(512, 4)
__global__ void gemm_head(const u16* __restrict__ A0, const u16* __restrict__ Wb,
                          const float* __restrict__ bias, const float* __restrict__ eW,
                          const float* __restrict__ eb,
                          float* __restrict__ outp, int outOffset, int Mr)
{
    __shared__ __align__(16) u16 As[128 * 32];
    __shared__ __align__(16) u16 Bs[256 * 32];
    __shared__ float bls[256], ews[256];
    __shared__ float sred[4][128];

    const int t = threadIdx.x;
    const int lane = t & 63;
    const int wid = t >> 6;
    const int wm = wid >> 2, wn = wid & 3;
    const int lb = lane & 15, lh = lane >> 4;
    const int row0 = blockIdx.x * 128;
    const int Kd = 512;

    if (t < 256) { bls[t] = bias[t]; ews[t] = eW[t]; }

    f32x4 acc[4][4];
#pragma unroll
    for (int i = 0; i < 4; ++i)
#pragma unroll
        for (int j = 0; j < 4; ++j) acc[i][j] = (f32x4){0.f, 0.f, 0.f, 0.f};

    for (int k0 = 0; k0 < Kd; k0 += 32) {
        __syncthreads();
        {
            int r = t >> 2, sl = t & 3;
            int row = row0 + r;
            bf16x8 val = {0,0,0,0,0,0,0,0};
            if (row < Mr) val = *(const bf16x8*)(A0 + (size_t)row * 512 + k0 + sl * 8);
            *(bf16x8*)&As[r * 32 + ((sl ^ ((r >> 1) & 3)) << 3)] = val;
        }
#pragma unroll
        for (int h = 0; h < 2; ++h) {
            int s = t + h * 512;
            int n = s >> 2, sl = s & 3;
            bf16x8 val = *(const bf16x8*)(Wb + (size_t)n * Kd + k0 + sl * 8);
            *(bf16x8*)&Bs[n * 32 + ((sl ^ ((n >> 1) & 3)) << 3)] = val;
        }
        __syncthreads();
        bf16x8 af[4], bfr[4];
#pragma unroll
        for (int i = 0; i < 4; ++i) {
            int r = wm * 64 + i * 16 + lb;
            af[i] = *(const bf16x8*)&As[r * 32 + ((lh ^ ((r >> 1) & 3)) << 3)];
        }
#pragma unroll
        for (int j = 0; j < 4; ++j) {
            int n = wn * 64 + j * 16 + lb;
            bfr[j] = *(const bf16x8*)&Bs[n * 32 + ((lh ^ ((n >> 1) & 3)) << 3)];
        }
#pragma unroll
        for (int i = 0; i < 4; ++i)
#pragma unroll
            for (int j = 0; j < 4; ++j)
                acc[i][j] = __builtin_amdgcn_mfma_f32_16x16x32_bf16(af[i], bfr[j], acc[i][j], 0, 0, 0);
    }

#pragma unroll
    for (int i = 0; i < 4; ++i) {
#pragma unroll
        for (int r = 0; r < 4; ++r) {
            float p = 0.f;
#pragma unroll
            for (int j = 0; j < 4; ++j) {
                int col = wn * 64 + j * 16 + lb;
                p += gelu_erf(acc[i][j][r] + bls[col]) * ews[col];
            }
            p += __shfl_xor(p, 1);
            p += __shfl_xor(p, 2);
            p += __shfl_xor(p, 4);
            p += __shfl_xor(p, 8);
            if (lb == 0) sred[wn][wm * 64 + i * 16 + lh * 4 + r] = p;
        }
    }
    __syncthreads();
    if (t < 128) {
        int row = row0 + t;
        if (row < Mr) {
            float s = sred[0][t] + sred[1][t] + sred[2][t] + sred[3][t] + eb[0];
            outp[outOffset + row] = 1.f / (1.f + expf(-s));
        }
    }
}

// logits = cl @ endW + endB ; softmax over 8 ; one wave per row
__global__ void node_head(const float* __restrict__ cl, const float* __restrict__ Wend,
                          const float* __restrict__ bend, float* __restrict__ out, int m)
{
    __shared__ float WsT[8 * 128];
    __shared__ float bs[8];
    int t = threadIdx.x;
    for (int i = t; i < 1024; i += 256) {
        int k = i >> 3, j = i & 7;
        WsT[j * 128 + k] = Wend[i];
    }
    if (t < 8) bs[t] = bend[t];
    __syncthreads();
    int gid = blockIdx.x * 256 + t;
    int wave = gid >> 6, lane = gid & 63;
    if (wave >= m) return;
    float v0 = cl[(size_t)wave * 128 + lane];
    float v1 = cl[(size_t)wave * 128 + lane + 64];
    float lg[8];
#pragma unroll
    for (int j = 0; j < 8; ++j) {
        float p = v0 * WsT[j * 128 + lane] + v1 * WsT[j * 128 + lane + 64];
#pragma unroll
        for (int o = 32; o; o >>= 1) p += __shfl_down(p, o);
        lg[j] = p;
    }
    if (lane == 0) {
        float mx = -1e30f;
#pragma unroll
        for (int j = 0; j < 8; ++j) { lg[j] += bs[j]; mx = fmaxf(mx, lg[j]); }
        float s = 0.f;
#pragma unroll
        for (int j = 0; j < 8; ++j) { lg[j] = expf(lg[j] - mx); s += lg[j]; }
        float inv = 1.f / s;
#pragma unroll
        for (int j = 0; j < 8; ++j) out[(size_t)wave * 8 + j] = lg[j] * inv;
    }
}

extern "C" void kernel_launch(void* const* d_in, const int* in_sizes, int n_in,
                              void* d_out, int out_size, void* d_ws, size_t ws_size,
                              hipStream_t stream)
{
    const float* X    = (const float*)d_in[0];
    const float* Y    = (const float*)d_in[1];
    const int*   EI   = (const int*)d_in[2];
    const int*   I0   = (const int*)d_in[3];
    const int*   I1   = (const int*)d_in[4];
    const float* bnG  = (const float*)d_in[5];
    const float* bnB  = (const float*)d_in[6];
    const float* Wlin = (const float*)d_in[7];
    const float* blin = (const float*)d_in[8];
    const float* tagWs= (const float*)d_in[9];
    const float* tagB = (const float*)d_in[10];
    const float* nlW0 = (const float*)d_in[11];
    const float* nlb0 = (const float*)d_in[12];
    const float* nlW1 = (const float*)d_in[13];
    const float* nlb1 = (const float*)d_in[14];
    const float* clW  = (const float*)d_in[15];
    const float* clb  = (const float*)d_in[16];
    const float* endW = (const float*)d_in[17];
    const float* endB = (const float*)d_in[18];
    const float* beG  = (const float*)d_in[19];
    const float* beB  = (const float*)d_in[20];
    const float* elW0 = (const float*)d_in[21];
    const float* elb0 = (const float*)d_in[22];
    const float* elW1 = (const float*)d_in[23];
    const float* elb1 = (const float*)d_in[24];
    const float* elEW = (const float*)d_in[25];
    const float* elEb = (const float*)d_in[26];

    const int N = NN, E = NE, P = NP;

    char* w = (char*)d_ws;
    size_t off = 0;
    auto alloc = [&](size_t bytes) -> void* {
        void* p = w + off;
        off += (bytes + 255) & ~(size_t)255;
        return p;
    };

    size_t zeroBytes = (size_t)(544 + 544 + 128 + 128) * 4 + (size_t)4 * N * 4;
    char* zr = (char*)alloc(zeroBytes);
    float* statS = (float*)zr;
    float* statQ = statS + 544;
    float* nodeS = statQ + 544;
    float* nodeQ = nodeS + 128;
    int* cnt    = (int*)(nodeQ + 128);
    int* cursor = cnt + N;
    int* cnt0   = cursor + N;
    int* cnt1   = cnt0 + N;

    int*   indptr = (int*)alloc((size_t)(N + 1) * 4);
    int*   part   = (int*)alloc((size_t)(NB_SCAN + 1) * 4);
    float* dinv   = (float*)alloc((size_t)N * 4);
    int*   csrS   = (int*)alloc((size_t)E * 4);
    float* sNode  = (float*)alloc(128 * 4);
    float* tNode  = (float*)alloc(128 * 4);
    float* sEdge  = (float*)alloc(544 * 4);
    float* tEdge  = (float*)alloc(544 * 4);
    float* b0p    = (float*)alloc(512 * 4);
    u16* Wlinb  = (u16*)alloc((size_t)128 * 128 * 2);
    u16* tagWsPb= (u16*)alloc((size_t)3 * 128 * 256 * 2);  // stacked pairs
    u16* tagW6b = (u16*)alloc((size_t)128 * 128 * 2);      // hop 6
    u16* nlW0b  = (u16*)alloc((size_t)256 * 256 * 2);
    u16* nlW1b  = (u16*)alloc((size_t)128 * 256 * 2);
    u16* clWb   = (u16*)alloc((size_t)128 * 128 * 2);
    u16* elW1b  = (u16*)alloc((size_t)256 * 512 * 2);
    u16* W0pb   = (u16*)alloc((size_t)512 * 544 * 2);
    u16*   hA   = (u16*)alloc((size_t)N * 128 * 2);   // h ping / aEmb
    u16*   hB   = (u16*)alloc((size_t)N * 128 * 2);   // h pong / houtb / Xb
    float* outT = (float*)alloc((size_t)N * 128 * 4); // TAG acc / a256+clbuf / o1

    if (ws_size < off) return;

    u16*   aEmb  = hA;
    u16*   houtb = hB;
    float* out_nodes = (float*)d_out;
    float* out_epred = (float*)d_out + (size_t)N * 8;

    hipMemsetAsync(zr, 0, zeroBytes, stream);

    convTB<<<(128*128 + 255)/256, 256, 0, stream>>>(Wlin, Wlinb, 128, 128, 1);
    conv_pair<<<(3*128*256 + 255)/256, 256, 0, stream>>>(tagWs, tagWsPb);
    convTB<<<(128*128 + 255)/256, 256, 0, stream>>>(tagWs + (size_t)KHOPS*128*128, tagW6b, 128, 128, 1);
    convTB<<<(256*256 + 255)/256, 256, 0, stream>>>(nlW0, nlW0b, 256, 256, 1);
    convTB<<<(256*128 + 255)/256, 256, 0, stream>>>(nlW1, nlW1b, 256, 128, 1);
    convTB<<<(128*128 + 255)/256, 256, 0, stream>>>(clW, clWb, 128, 128, 1);
    convTB<<<(512*256 + 255)/256, 256, 0, stream>>>(elW1, elW1b, 512, 256, 1);

    col_stats<0><<<1024, 256, 0, stream>>>(X, N, 7, nullptr, nullptr, nodeS, nodeQ, 0, 0);
    bn_finalize<<<1, 128, 0, stream>>>(nodeS, nodeQ, bnG, bnB, sNode, tNode, 128, (float)N, 1e-5f);

    dim3 g1((N + 127) / 128, 1);
    // h0 = hA = bf16(gelu(BN(X) @ Wlin + blin))
    gemm_mfma<3, 1, 0, 1><<<g1, 256, 0, stream>>>(X, nullptr, nullptr, nullptr, nullptr, 0,
                                                  sNode, tNode, Wlinb, blin, hA, nullptr, N, 128, 128, 128);

    hist_add<<<2048, 256, 0, stream>>>(EI + E, E, cnt);
    hist_add2<<<1024, 256, 0, stream>>>(I0, I1, P, cnt0, cnt1);
    scan1<<<NB_SCAN, 1024, 0, stream>>>(cnt, indptr, part, N);
    scan2<<<1, 256, 0, stream>>>(part, NB_SCAN);
    scan3<<<NB_SCAN, 1024, 0, stream>>>(indptr, part, cnt, dinv, N);
    csr_build<<<2048, 256, 0, stream>>>(EI, EI + E, E, indptr, cursor, csrS);

    // ---- TAGConv: 3 paired K=256 GEMMs + fused final hop ----
    int spmmGrid = (N * 64 + 255) / 256;
    spmm_hop<<<spmmGrid, 256, 0, stream>>>(hA, hB, indptr, csrS, dinv);          // h1
    gemm_mfma<5, 0, 0, 0><<<g1, 256, 0, stream>>>(hA, hB, nullptr, nullptr, nullptr, 0,
                                                  nullptr, nullptr, tagWsPb, nullptr, outT, nullptr,
                                                  N, 256, 128, 0);
    spmm_hop<<<spmmGrid, 256, 0, stream>>>(hB, hA, indptr, csrS, dinv);          // h2
    spmm_hop<<<spmmGrid, 256, 0, stream>>>(hA, hB, indptr, csrS, dinv);          // h3
    gemm_mfma<5, 0, 1, 0><<<g1, 256, 0, stream>>>(hA, hB, nullptr, nullptr, nullptr, 0,
                                                  nullptr, nullptr, tagWsPb + (size_t)1*128*256,
                                                  nullptr, outT, outT, N, 256, 128, 0);
    spmm_hop<<<spmmGrid, 256, 0, stream>>>(hB, hA, indptr, csrS, dinv);          // h4
    spmm_hop<<<spmmGrid, 256, 0, stream>>>(hA, hB, indptr, csrS, dinv);          // h5
    gemm_mfma<5, 0, 1, 0><<<g1, 256, 0, stream>>>(hA, hB, nullptr, nullptr, nullptr, 0,
                                                  nullptr, nullptr, tagWsPb + (size_t)2*128*256,
                                                  nullptr, outT, outT, N, 256, 128, 0);
    spmm_hop<<<spmmGrid, 256, 0, stream>>>(hB, hA, indptr, csrS, dinv);          // h6
    // final: houtb(hB) = bf16(gelu(outT + h6@W6 + tagB))
    gemm_mfma<0, 1, 1, 1><<<g1, 256, 0, stream>>>(hA, nullptr, nullptr, nullptr, nullptr, 0,
                                                  nullptr, nullptr, tagW6b, tagB, houtb, outT,
                                                  N, 128, 128, 128);

    // ---- node MLP ----
    u16*   a256  = (u16*)outT;
    float* clbuf = outT;
    {
        dim3 gA((N + 127) / 128, 1);
        gemm_wide<1, 1, 1, 256><<<gA, 512, 0, stream>>>(X, houtb, nullptr, nullptr, nullptr, 0,
                                                        sNode, tNode, nlW0b, nlb0, a256, N, 256, 256);
        dim3 gB((N + 127) / 128, 1);
        gemm_mfma<0, 1, 0, 1><<<gB, 256, 0, stream>>>(a256, nullptr, nullptr, nullptr, nullptr, 0,
                                                      nullptr, nullptr, nlW1b, nlb1, aEmb, nullptr,
                                                      N, 256, 128, 256);
        gemm_mfma<0, 1, 0, 0><<<gB, 256, 0, stream>>>(aEmb, nullptr, nullptr, nullptr, nullptr, 0,
                                                      nullptr, nullptr, clWb, clb, clbuf, nullptr,
                                                      N, 128, 128, 128);
        node_head<<<(N + 3) / 4, 256, 0, stream>>>(clbuf, endW, endB, out_nodes, N);
    }

    // Xb = bf16(X) into hB (houtb dead after node MLP)
    u16* Xb = hB;
    convB<<<2048, 256, 0, stream>>>(X, Xb, N * 128 / 4);

    col_stats<1><<<1024, 256, 0, stream>>>(aEmb, N, 7, cnt0, cnt1, statS, statQ, 0, 128);
    col_stats<1><<<1024, 256, 0, stream>>>(Xb,   N, 7, cnt0, cnt1, statS, statQ, 256, 384);
    col_stats<0><<<1024, 256, 0, stream>>>(Y,    P, 5, nullptr, nullptr, statS, statQ, 512, 0);
    bn_finalize<<<3, 256, 0, stream>>>(statS, statQ, beG, beB, sEdge, tEdge, 544, (float)P, 1.0f);
    fold_wT<<<(512*544 + 255)/256, 256, 0, stream>>>(elW0, sEdge, W0pb);
    fold_b<<<2, 256, 0, stream>>>(elW0, elb0, tEdge, b0p);

    // ---- edge MLP: L1 in one 512-wide pass, then fused L2+head ----
    u16* o1 = (u16*)outT;
    for (int pb = 0; pb < P; pb += ECHK) {
        int m = (P - pb < ECHK) ? (P - pb) : ECHK;
        dim3 gA((m + 127) / 128, 1);
        gemm_wide<2, 1, 1, 512><<<gA, 512, 0, stream>>>(aEmb, Xb, Y, I0, I1, pb,
                                                        nullptr, nullptr, W0pb, b0p, o1, m, 544, 512);
        dim3 gB((m + 127) / 128, 1);
        gemm_head<<<gB, 512, 0, stream>>>(o1, elW1b, elb1, elEW, elEb, out_epred, pb, m);
    }
}

// Round 10
// 2277.993 us; speedup vs baseline: 2.1283x; 2.1283x over previous
//
#include <hip/hip_runtime.h>
#include <math.h>

#define NN 100000
#define NE 1600000
#define NP 500000
#define KHOPS 6
#define ECHK 50000          // edge chunk rows; o1 [ECHK,512] bf16 = 51.2 MB = outT
#define NB_SCAN ((NN + 1023) / 1024)

typedef unsigned short u16;
typedef short bf16x8 __attribute__((ext_vector_type(8)));
typedef float f32x4 __attribute__((ext_vector_type(4)));

__device__ __forceinline__ float gelu_erf(float x) {
    return 0.5f * x * (1.0f + erff(x * 0.70710678118654752f));
}
__device__ __forceinline__ float b2f(u16 u) {
    return __uint_as_float(((unsigned int)u) << 16);
}
__device__ __forceinline__ u16 f2b(float f) {
    unsigned int x = __float_as_uint(f);
    return (u16)((x + 0x7FFFu + ((x >> 16) & 1u)) >> 16);
}
__device__ __forceinline__ bf16x8 cvt8(float4 a, float4 b) {
    bf16x8 v;
    v[0]=(short)f2b(a.x); v[1]=(short)f2b(a.y); v[2]=(short)f2b(a.z); v[3]=(short)f2b(a.w);
    v[4]=(short)f2b(b.x); v[5]=(short)f2b(b.y); v[6]=(short)f2b(b.z); v[7]=(short)f2b(b.w);
    return v;
}

// ---------------- column statistics
template<int BF>
__global__ void col_stats(const void* __restrict__ Matv, int rows, int lc,
                          const int* __restrict__ w0, const int* __restrict__ w1,
                          float* __restrict__ sums, float* __restrict__ sumsq,
                          int base0, int base1)
{
    __shared__ float red[256];
    const int t = threadIdx.x;
    const int C = 1 << lc;
    const long total = (long)rows << lc;
    const long stride = (long)gridDim.x * 256;
    float s0 = 0.f, q0 = 0.f, s1 = 0.f, q1 = 0.f;
    for (long idx = (long)blockIdx.x * 256 + t; idx < total; idx += stride) {
        int r = (int)(idx >> lc);
        float v = BF ? b2f(((const u16*)Matv)[idx]) : ((const float*)Matv)[idx];
        float f0 = w0 ? (float)w0[r] : 1.0f;
        s0 += f0 * v;
        q0 += f0 * v * v;
        if (w1) {
            float f1 = (float)w1[r];
            s1 += f1 * v;
            q1 += f1 * v * v;
        }
    }
    red[t] = s0; __syncthreads();
    if (t < C) { float x = 0.f; for (int k = t; k < 256; k += C) x += red[k]; atomicAdd(&sums[base0 + t], x); }
    __syncthreads();
    red[t] = q0; __syncthreads();
    if (t < C) { float x = 0.f; for (int k = t; k < 256; k += C) x += red[k]; atomicAdd(&sumsq[base0 + t], x); }
    __syncthreads();
    if (w1) {
        red[t] = s1; __syncthreads();
        if (t < C) { float x = 0.f; for (int k = t; k < 256; k += C) x += red[k]; atomicAdd(&sums[base1 + t], x); }
        __syncthreads();
        red[t] = q1; __syncthreads();
        if (t < C) { float x = 0.f; for (int k = t; k < 256; k += C) x += red[k]; atomicAdd(&sumsq[base1 + t], x); }
    }
}

__global__ void bn_finalize(const float* __restrict__ sums, const float* __restrict__ sumsq,
                            const float* __restrict__ g, const float* __restrict__ b,
                            float* __restrict__ s, float* __restrict__ t,
                            int C, float count, float eps)
{
    int c = blockIdx.x * blockDim.x + threadIdx.x;
    if (c < C) {
        float mu = sums[c] / count;
        float var = sumsq[c] / count - mu * mu;
        float sc = g[c] * rsqrtf(var + eps);
        s[c] = sc;
        t[c] = b[c] - mu * sc;
    }
}

__global__ void hist_add(const int* __restrict__ idx, int n, int* __restrict__ cnt)
{
    int stride = gridDim.x * blockDim.x;
    for (int i = blockIdx.x * blockDim.x + threadIdx.x; i < n; i += stride)
        atomicAdd(&cnt[idx[i]], 1);
}

__global__ void hist_add2(const int* __restrict__ i0, const int* __restrict__ i1, int n,
                          int* __restrict__ c0, int* __restrict__ c1)
{
    int stride = gridDim.x * blockDim.x;
    for (int i = blockIdx.x * blockDim.x + threadIdx.x; i < n; i += stride) {
        atomicAdd(&c0[i0[i]], 1);
        atomicAdd(&c1[i1[i]], 1);
    }
}

__global__ void scan1(const int* __restrict__ cnt, int* __restrict__ ex,
                      int* __restrict__ part, int n)
{
    __shared__ int buf[1024];
    int b = blockIdx.x, t = threadIdx.x;
    int i = b * 1024 + t;
    int v = (i < n) ? cnt[i] : 0;
    buf[t] = v;
    __syncthreads();
    int incl = v;
    for (int o = 1; o < 1024; o <<= 1) {
        int tmp = (t >= o) ? buf[t - o] : 0;
        __syncthreads();
        incl += tmp;
        buf[t] = incl;
        __syncthreads();
    }
    if (i < n) ex[i] = incl - v;
    if (t == 1023) part[b] = incl;
}

__global__ void scan2(int* __restrict__ part, int nb)
{
    __shared__ int s[256];
    int t = threadIdx.x;
    if (t < nb) s[t] = part[t];
    __syncthreads();
    if (t == 0) {
        int run = 0;
        for (int b = 0; b < nb; ++b) { int x = s[b]; part[b] = run; run += x; }
        part[nb] = run;
    }
}

__global__ void scan3(int* __restrict__ indptr, const int* __restrict__ part,
                      const int* __restrict__ cnt, float* __restrict__ dinv, int n)
{
    int b = blockIdx.x, t = threadIdx.x;
    int i = b * 1024 + t;
    if (i < n) {
        indptr[i] += part[b];
        int c = cnt[i];
        dinv[i] = (c > 0) ? rsqrtf((float)c) : 0.f;
    }
    if (b == 0 && t == 0) indptr[n] = part[NB_SCAN];
}

__global__ void csr_build(const int* __restrict__ src, const int* __restrict__ dst, int n,
                          const int* __restrict__ indptr, int* __restrict__ cursor,
                          int* __restrict__ csrS)
{
    int stride = gridDim.x * blockDim.x;
    for (int e = blockIdx.x * blockDim.x + threadIdx.x; e < n; e += stride) {
        int s = src[e], d = dst[e];
        int pos = indptr[d] + atomicAdd(&cursor[d], 1);
        csrS[pos] = s;
    }
}

// hout[n, 2l..2l+1] via ushort2; 8-edge unroll
__global__ void spmm_hop(const u16* __restrict__ hin, u16* __restrict__ hout,
                         const int* __restrict__ indptr, const int* __restrict__ csrS,
                         const float* __restrict__ dinv)
{
    int gid = blockIdx.x * blockDim.x + threadIdx.x;
    int node = gid >> 6;
    int lane = gid & 63;
    if (node >= NN) return;
    float dn = dinv[node];
    int beg = indptr[node], end = indptr[node + 1];
    float a0 = 0.f, a1 = 0.f;
    int e = beg;
    for (; e + 7 < end; e += 8) {
        int sidx[8];
        ushort2 pv[8];
#pragma unroll
        for (int u = 0; u < 8; ++u) sidx[u] = csrS[e + u];
#pragma unroll
        for (int u = 0; u < 8; ++u)
            pv[u] = *(const ushort2*)(hin + (size_t)sidx[u] * 128 + lane * 2);
#pragma unroll
        for (int u = 0; u < 8; ++u) {
            float wv = dn * dinv[sidx[u]];
            a0 = fmaf(wv, b2f(pv[u].x), a0);
            a1 = fmaf(wv, b2f(pv[u].y), a1);
        }
    }
    for (; e < end; ++e) {
        int s0 = csrS[e];
        float w0 = dn * dinv[s0];
        ushort2 p0 = *(const ushort2*)(hin + (size_t)s0 * 128 + lane * 2);
        a0 = fmaf(w0, b2f(p0.x), a0);
        a1 = fmaf(w0, b2f(p0.y), a1);
    }
    ushort2 o;
    o.x = f2b(a0); o.y = f2b(a1);
    *(ushort2*)(hout + (size_t)node * 128 + lane * 2) = o;
}

__global__ void convTB(const float* __restrict__ in, u16* __restrict__ out,
                       int K, int Nc, int B)
{
    int per = K * Nc;
    int i = blockIdx.x * blockDim.x + threadIdx.x;
    if (i < per * B) {
        int m = i / per, r = i - m * per;
        int n = r / K, k = r - n * K;
        out[i] = f2b(in[(size_t)m * per + (size_t)k * Nc + n]);
    }
}

// stacked TAG pair weights: out[p][n][k(0..255)] = bf16(Ws[2p + (k>=128)][k&127][n])
__global__ void conv_pair(const float* __restrict__ Ws, u16* __restrict__ out)
{
    int i = blockIdx.x * blockDim.x + threadIdx.x;
    if (i < 3 * 128 * 256) {
        int p = i >> 15;
        int r = i & 32767;
        int n = r >> 8, k = r & 255;
        int hop = 2 * p + (k >> 7);
        out[i] = f2b(Ws[(size_t)hop * 16384 + (size_t)(k & 127) * 128 + n]);
    }
}

// plain fp32 -> bf16 convert, float4-vectorized
__global__ void convB(const float* __restrict__ in, u16* __restrict__ out, int n4)
{
    int stride = gridDim.x * blockDim.x;
    for (int i = blockIdx.x * blockDim.x + threadIdx.x; i < n4; i += stride) {
        float4 v = ((const float4*)in)[i];
        ushort4 o;
        o.x = f2b(v.x); o.y = f2b(v.y); o.z = f2b(v.z); o.w = f2b(v.w);
        ((ushort4*)out)[i] = o;
    }
}

__global__ void fold_wT(const float* __restrict__ W0, const float* __restrict__ s,
                        u16* __restrict__ out)
{
    int i = blockIdx.x * blockDim.x + threadIdx.x;
    if (i < 512 * 544) {
        int n = i / 544, k = i - n * 544;
        out[i] = f2b(s[k] * W0[(size_t)k * 512 + n]);
    }
}

__global__ void fold_b(const float* __restrict__ W0, const float* __restrict__ b0,
                       const float* __restrict__ tv, float* __restrict__ bp)
{
    int j = blockIdx.x * blockDim.x + threadIdx.x;
    if (j < 512) {
        float s = b0[j];
        for (int k = 0; k < 544; ++k) s = fmaf(tv[k], W0[k * 512 + j], s);
        bp[j] = s;
    }
}

// ---- shared A-tile loader ----
// AMODE 0: dense bf16 A0, lda
// AMODE 1: concat [BN(fp32 A0, sv/tv) | bf16 A1], stride 128, Kd=256
// AMODE 2: edge gather [aEmb[i0]|aEmb[i1]|Xb[i0]|Xb[i1]|bf16(Y)], Kd=544
// AMODE 3: BN-on-the-fly fp32 A0, stride 128
// AMODE 5: concat [bf16 A0 | bf16 A1], stride 128, Kd=256
template<int AMODE>
__device__ __forceinline__ bf16x8 load_a_slot(
    const void* __restrict__ A0v, const void* __restrict__ A1v,
    const float* __restrict__ Yp, const int* __restrict__ i0s, const int* __restrict__ i1s,
    int rowOffset, const float* __restrict__ sv, const float* __restrict__ tv,
    int row, int r, int k0, int sl, int Mr, int lda)
{
    bf16x8 val = {0, 0, 0, 0, 0, 0, 0, 0};
    if (row < Mr) {
        if (AMODE == 0) {
            val = *(const bf16x8*)((const u16*)A0v + (size_t)row * lda + k0 + sl * 8);
        } else if (AMODE == 5) {
            int c = k0 + sl * 8;
            const u16* Ap = (c < 128) ? (const u16*)A0v : (const u16*)A1v;
            val = *(const bf16x8*)(Ap + (size_t)row * 128 + (c & 127));
        } else if (AMODE == 1) {
            int c = k0 + sl * 8;
            if (c < 128) {
                const float* xp = (const float*)A0v + (size_t)row * 128 + c;
                float4 x0 = *(const float4*)xp, x1 = *(const float4*)(xp + 4);
                float4 s0 = *(const float4*)(sv + c), s1 = *(const float4*)(sv + c + 4);
                float4 t0 = *(const float4*)(tv + c), t1 = *(const float4*)(tv + c + 4);
                float4 a = make_float4(fmaf(x0.x,s0.x,t0.x), fmaf(x0.y,s0.y,t0.y),
                                       fmaf(x0.z,s0.z,t0.z), fmaf(x0.w,s0.w,t0.w));
                float4 b = make_float4(fmaf(x1.x,s1.x,t1.x), fmaf(x1.y,s1.y,t1.y),
                                       fmaf(x1.z,s1.z,t1.z), fmaf(x1.w,s1.w,t1.w));
                val = cvt8(a, b);
            } else {
                val = *(const bf16x8*)((const u16*)A1v + (size_t)row * 128 + (c - 128));
            }
        } else if (AMODE == 3) {
            int c = k0 + sl * 8;
            const float* xp = (const float*)A0v + (size_t)row * 128 + c;
            float4 x0 = *(const float4*)xp, x1 = *(const float4*)(xp + 4);
            float4 s0 = *(const float4*)(sv + c), s1 = *(const float4*)(sv + c + 4);
            float4 t0 = *(const float4*)(tv + c), t1 = *(const float4*)(tv + c + 4);
            float4 a = make_float4(fmaf(x0.x,s0.x,t0.x), fmaf(x0.y,s0.y,t0.y),
                                   fmaf(x0.z,s0.z,t0.z), fmaf(x0.w,s0.w,t0.w));
            float4 b = make_float4(fmaf(x1.x,s1.x,t1.x), fmaf(x1.y,s1.y,t1.y),
                                   fmaf(x1.z,s1.z,t1.z), fmaf(x1.w,s1.w,t1.w));
            val = cvt8(a, b);
        } else { // AMODE 2
            int seg = k0 >> 7;
            int c = (k0 & 127) + sl * 8;
            if (seg == 0) {
                val = *(const bf16x8*)((const u16*)A0v + (size_t)i0s[r] * 128 + c);
            } else if (seg == 1) {
                val = *(const bf16x8*)((const u16*)A0v + (size_t)i1s[r] * 128 + c);
            } else if (seg == 2) {
                val = *(const bf16x8*)((const u16*)A1v + (size_t)i0s[r] * 128 + c);
            } else if (seg == 3) {
                val = *(const bf16x8*)((const u16*)A1v + (size_t)i1s[r] * 128 + c);
            } else {
                const float* yp = Yp + (size_t)(rowOffset + row) * 32 + sl * 8;
                val = cvt8(*(const float4*)yp, *(const float4*)(yp + 4));
            }
        }
    }
    return val;
}

// ------------- 4-wave MFMA GEMM: tile 128x128, BK=32
template<int AMODE, int ACT, int ACCUM, int OUTBF>
__launch_bounds__(256, 2)
__global__ void gemm_mfma(const void* __restrict__ A0v, const void* __restrict__ A1v,
                          const float* __restrict__ Yp,
                          const int* __restrict__ I0, const int* __restrict__ I1,
                          int rowOffset,
                          const float* __restrict__ sv, const float* __restrict__ tv,
                          const u16* __restrict__ Wb, const float* __restrict__ bias,
                          void* __restrict__ Cv, const float* __restrict__ Cacc,
                          int Mr, int Kd, int Nc, int lda)
{
    __shared__ __align__(16) u16 As[128 * 32];
    __shared__ __align__(16) u16 Bs[128 * 32];
    __shared__ int i0s[128], i1s[128];

    const int t = threadIdx.x;
    const int lane = t & 63;
    const int wid = t >> 6;
    const int wm = wid >> 1, wn = wid & 1;
    const int lb = lane & 15, lh = lane >> 4;
    const int row0 = blockIdx.x * 128;
    const int colb = blockIdx.y * 128;

    if (AMODE == 2) {
        if (t < 128) {
            int r = row0 + t;
            i0s[t] = (r < Mr) ? I0[rowOffset + r] : 0;
        } else {
            int r = row0 + (t - 128);
            i1s[t - 128] = (r < Mr) ? I1[rowOffset + r] : 0;
        }
    }

    f32x4 acc[4][4];
#pragma unroll
    for (int i = 0; i < 4; ++i)
#pragma unroll
        for (int j = 0; j < 4; ++j) acc[i][j] = (f32x4){0.f, 0.f, 0.f, 0.f};

    for (int k0 = 0; k0 < Kd; k0 += 32) {
        __syncthreads();
#pragma unroll
        for (int h = 0; h < 2; ++h) {
            int s = t + h * 256;
            int r = s >> 2, sl = s & 3;
            bf16x8 val = load_a_slot<AMODE>(A0v, A1v, Yp, i0s, i1s, rowOffset, sv, tv,
                                            row0 + r, r, k0, sl, Mr, lda);
            *(bf16x8*)&As[r * 32 + ((sl ^ ((r >> 1) & 3)) << 3)] = val;
        }
#pragma unroll
        for (int h = 0; h < 2; ++h) {
            int s = t + h * 256;
            int n = s >> 2, sl = s & 3;
            bf16x8 val = *(const bf16x8*)(Wb + (size_t)(colb + n) * Kd + k0 + sl * 8);
            *(bf16x8*)&Bs[n * 32 + ((sl ^ ((n >> 1) & 3)) << 3)] = val;
        }
        __syncthreads();
        bf16x8 af[4], bfr[4];
#pragma unroll
        for (int i = 0; i < 4; ++i) {
            int r = wm * 64 + i * 16 + lb;
            af[i] = *(const bf16x8*)&As[r * 32 + ((lh ^ ((r >> 1) & 3)) << 3)];
        }
#pragma unroll
        for (int j = 0; j < 4; ++j) {
            int n = wn * 64 + j * 16 + lb;
            bfr[j] = *(const bf16x8*)&Bs[n * 32 + ((lh ^ ((n >> 1) & 3)) << 3)];
        }
#pragma unroll
        for (int i = 0; i < 4; ++i)
#pragma unroll
            for (int j = 0; j < 4; ++j)
                acc[i][j] = __builtin_amdgcn_mfma_f32_16x16x32_bf16(af[i], bfr[j], acc[i][j], 0, 0, 0);
    }

#pragma unroll
    for (int i = 0; i < 4; ++i) {
#pragma unroll
        for (int j = 0; j < 4; ++j) {
            int col = colb + wn * 64 + j * 16 + lb;
#pragma unroll
            for (int r = 0; r < 4; ++r) {
                int row = row0 + wm * 64 + i * 16 + lh * 4 + r;
                if (row < Mr) {
                    size_t off = (size_t)row * Nc + col;
                    float v = acc[i][j][r];
                    if (ACCUM) v += Cacc[off];
                    if (ACT) v = gelu_erf(v + bias[col]);
                    if (OUTBF) ((u16*)Cv)[off] = f2b(v);
                    else       ((float*)Cv)[off] = v;
                }
            }
        }
    }
}

// ------------- 8-wave MFMA GEMM: tile 128x256, BK=32 (round-8 proven config)
template<int AMODE, int ACT, int OUTBF>
__launch_bounds__(512, 4)
__global__ void gemm_wide(const void* __restrict__ A0v, const void* __restrict__ A1v,
                          const float* __restrict__ Yp,
                          const int* __restrict__ I0, const int* __restrict__ I1,
                          int rowOffset,
                          const float* __restrict__ sv, const float* __restrict__ tv,
                          const u16* __restrict__ Wb, const float* __restrict__ bias,
                          void* __restrict__ Cv, int Mr, int Kd, int Nc)
{
    __shared__ __align__(16) u16 As[128 * 32];
    __shared__ __align__(16) u16 Bs[256 * 32];
    __shared__ int i0s[128], i1s[128];

    const int t = threadIdx.x;
    const int lane = t & 63;
    const int wid = t >> 6;
    const int wm = wid >> 2, wn = wid & 3;
    const int lb = lane & 15, lh = lane >> 4;
    const int row0 = blockIdx.x * 128;
    const int colb = blockIdx.y * 256;

    if (AMODE == 2) {
        if (t < 128) {
            int r = row0 + t;
            i0s[t] = (r < Mr) ? I0[rowOffset + r] : 0;
        } else if (t < 256) {
            int r = row0 + (t - 128);
            i1s[t - 128] = (r < Mr) ? I1[rowOffset + r] : 0;
        }
    }

    f32x4 acc[4][4];
#pragma unroll
    for (int i = 0; i < 4; ++i)
#pragma unroll
        for (int j = 0; j < 4; ++j) acc[i][j] = (f32x4){0.f, 0.f, 0.f, 0.f};

    for (int k0 = 0; k0 < Kd; k0 += 32) {
        __syncthreads();
        {
            int r = t >> 2, sl = t & 3;
            bf16x8 val = load_a_slot<AMODE>(A0v, A1v, Yp, i0s, i1s, rowOffset, sv, tv,
                                            row0 + r, r, k0, sl, Mr, 0);
            *(bf16x8*)&As[r * 32 + ((sl ^ ((r >> 1) & 3)) << 3)] = val;
        }
#pragma unroll
        for (int h = 0; h < 2; ++h) {
            int s = t + h * 512;
            int n = s >> 2, sl = s & 3;
            bf16x8 val = *(const bf16x8*)(Wb + (size_t)(colb + n) * Kd + k0 + sl * 8);
            *(bf16x8*)&Bs[n * 32 + ((sl ^ ((n >> 1) & 3)) << 3)] = val;
        }
        __syncthreads();
        bf16x8 af[4], bfr[4];
#pragma unroll
        for (int i = 0; i < 4; ++i) {
            int r = wm * 64 + i * 16 + lb;
            af[i] = *(const bf16x8*)&As[r * 32 + ((lh ^ ((r >> 1) & 3)) << 3)];
        }
#pragma unroll
        for (int j = 0; j < 4; ++j) {
            int n = wn * 64 + j * 16 + lb;
            bfr[j] = *(const bf16x8*)&Bs[n * 32 + ((lh ^ ((n >> 1) & 3)) << 3)];
        }
#pragma unroll
        for (int i = 0; i < 4; ++i)
#pragma unroll
            for (int j = 0; j < 4; ++j)
                acc[i][j] = __builtin_amdgcn_mfma_f32_16x16x32_bf16(af[i], bfr[j], acc[i][j], 0, 0, 0);
    }

#pragma unroll
    for (int i = 0; i < 4; ++i) {
#pragma unroll
        for (int j = 0; j < 4; ++j) {
            int col = colb + wn * 64 + j * 16 + lb;
#pragma unroll
            for (int r = 0; r < 4; ++r) {
                int row = row0 + wm * 64 + i * 16 + lh * 4 + r;
                if (row < Mr) {
                    size_t off = (size_t)row * Nc + col;
                    float v = acc[i][j][r];
                    if (ACT) v = gelu_erf(v + bias[col]);
                    if (OUTBF) ((u16*)Cv)[off] = f2b(v);
                    else       ((float*)Cv)[off] = v;
                }
            }
        }
    }
}

// ------------- edge layer-2 + sigmoid head fused
__launch_bounds__(512, 4)
__global__ void gemm_head(const u16* __restrict__ A0, const u16* __restrict__ Wb,
                          const float* __restrict__ bias, const float* __restrict__ eW,
                          const float* __restrict__ eb,
                          float* __restrict__ outp, int outOffset, int Mr)
{
    __shared__ __align__(16) u16 As[128 * 32];
    __shared__ __align__(16) u16 Bs[256 * 32];
    __shared__ float bls[256], ews[256];
    __shared__ float sred[4][128];

    const int t = threadIdx.x;
    const int lane = t & 63;
    const int wid = t >> 6;
    const int wm = wid >> 2, wn = wid & 3;
    const int lb = lane & 15, lh = lane >> 4;
    const int row0 = blockIdx.x * 128;
    const int Kd = 512;

    if (t < 256) { bls[t] = bias[t]; ews[t] = eW[t]; }

    f32x4 acc[4][4];
#pragma unroll
    for (int i = 0; i < 4; ++i)
#pragma unroll
        for (int j = 0; j < 4; ++j) acc[i][j] = (f32x4){0.f, 0.f, 0.f, 0.f};

    for (int k0 = 0; k0 < Kd; k0 += 32) {
        __syncthreads();
        {
            int r = t >> 2, sl = t & 3;
            int row = row0 + r;
            bf16x8 val = {0,0,0,0,0,0,0,0};
            if (row < Mr) val = *(const bf16x8*)(A0 + (size_t)row * 512 + k0 + sl * 8);
            *(bf16x8*)&As[r * 32 + ((sl ^ ((r >> 1) & 3)) << 3)] = val;
        }
#pragma unroll
        for (int h = 0; h < 2; ++h) {
            int s = t + h * 512;
            int n = s >> 2, sl = s & 3;
            bf16x8 val = *(const bf16x8*)(Wb + (size_t)n * Kd + k0 + sl * 8);
            *(bf16x8*)&Bs[n * 32 + ((sl ^ ((n >> 1) & 3)) << 3)] = val;
        }
        __syncthreads();
        bf16x8 af[4], bfr[4];
#pragma unroll
        for (int i = 0; i < 4; ++i) {
            int r = wm * 64 + i * 16 + lb;
            af[i] = *(const bf16x8*)&As[r * 32 + ((lh ^ ((r >> 1) & 3)) << 3)];
        }
#pragma unroll
        for (int j = 0; j < 4; ++j) {
            int n = wn * 64 + j * 16 + lb;
            bfr[j] = *(const bf16x8*)&Bs[n * 32 + ((lh ^ ((n >> 1) & 3)) << 3)];
        }
#pragma unroll
        for (int i = 0; i < 4; ++i)
#pragma unroll
            for (int j = 0; j < 4; ++j)
                acc[i][j] = __builtin_amdgcn_mfma_f32_16x16x32_bf16(af[i], bfr[j], acc[i][j], 0, 0, 0);
    }

#pragma unroll
    for (int i = 0; i < 4; ++i) {
#pragma unroll
        for (int r = 0; r < 4; ++r) {
            float p = 0.f;
#pragma unroll
            for (int j = 0; j < 4; ++j) {
                int col = wn * 64 + j * 16 + lb;
                p += gelu_erf(acc[i][j][r] + bls[col]) * ews[col];
            }
            p += __shfl_xor(p, 1);
            p += __shfl_xor(p, 2);
            p += __shfl_xor(p, 4);
            p += __shfl_xor(p, 8);
            if (lb == 0) sred[wn][wm * 64 + i * 16 + lh * 4 + r] = p;
        }
    }
    __syncthreads();
    if (t < 128) {
        int row = row0 + t;
        if (row < Mr) {
            float s = sred[0][t] + sred[1][t] + sred[2][t] + sred[3][t] + eb[0];
            outp[outOffset + row] = 1.f / (1.f + expf(-s));
        }
    }
}

// logits = cl @ endW + endB ; softmax over 8 ; one wave per row
__global__ void node_head(const float* __restrict__ cl, const float* __restrict__ Wend,
                          const float* __restrict__ bend, float* __restrict__ out, int m)
{
    __shared__ float WsT[8 * 128];
    __shared__ float bs[8];
    int t = threadIdx.x;
    for (int i = t; i < 1024; i += 256) {
        int k = i >> 3, j = i & 7;
        WsT[j * 128 + k] = Wend[i];
    }
    if (t < 8) bs[t] = bend[t];
    __syncthreads();
    int gid = blockIdx.x * 256 + t;
    int wave = gid >> 6, lane = gid & 63;
    if (wave >= m) return;
    float v0 = cl[(size_t)wave * 128 + lane];
    float v1 = cl[(size_t)wave * 128 + lane + 64];
    float lg[8];
#pragma unroll
    for (int j = 0; j < 8; ++j) {
        float p = v0 * WsT[j * 128 + lane] + v1 * WsT[j * 128 + lane + 64];
#pragma unroll
        for (int o = 32; o; o >>= 1) p += __shfl_down(p, o);
        lg[j] = p;
    }
    if (lane == 0) {
        float mx = -1e30f;
#pragma unroll
        for (int j = 0; j < 8; ++j) { lg[j] += bs[j]; mx = fmaxf(mx, lg[j]); }
        float s = 0.f;
#pragma unroll
        for (int j = 0; j < 8; ++j) { lg[j] = expf(lg[j] - mx); s += lg[j]; }
        float inv = 1.f / s;
#pragma unroll
        for (int j = 0; j < 8; ++j) out[(size_t)wave * 8 + j] = lg[j] * inv;
    }
}

extern "C" void kernel_launch(void* const* d_in, const int* in_sizes, int n_in,
                              void* d_out, int out_size, void* d_ws, size_t ws_size,
                              hipStream_t stream)
{
    const float* X    = (const float*)d_in[0];
    const float* Y    = (const float*)d_in[1];
    const int*   EI   = (const int*)d_in[2];
    const int*   I0   = (const int*)d_in[3];
    const int*   I1   = (const int*)d_in[4];
    const float* bnG  = (const float*)d_in[5];
    const float* bnB  = (const float*)d_in[6];
    const float* Wlin = (const float*)d_in[7];
    const float* blin = (const float*)d_in[8];
    const float* tagWs= (const float*)d_in[9];
    const float* tagB = (const float*)d_in[10];
    const float* nlW0 = (const float*)d_in[11];
    const float* nlb0 = (const float*)d_in[12];
    const float* nlW1 = (const float*)d_in[13];
    const float* nlb1 = (const float*)d_in[14];
    const float* clW  = (const float*)d_in[15];
    const float* clb  = (const float*)d_in[16];
    const float* endW = (const float*)d_in[17];
    const float* endB = (const float*)d_in[18];
    const float* beG  = (const float*)d_in[19];
    const float* beB  = (const float*)d_in[20];
    const float* elW0 = (const float*)d_in[21];
    const float* elb0 = (const float*)d_in[22];
    const float* elW1 = (const float*)d_in[23];
    const float* elb1 = (const float*)d_in[24];
    const float* elEW = (const float*)d_in[25];
    const float* elEb = (const float*)d_in[26];

    const int N = NN, E = NE, P = NP;

    char* w = (char*)d_ws;
    size_t off = 0;
    auto alloc = [&](size_t bytes) -> void* {
        void* p = w + off;
        off += (bytes + 255) & ~(size_t)255;
        return p;
    };

    size_t zeroBytes = (size_t)(544 + 544 + 128 + 128) * 4 + (size_t)4 * N * 4;
    char* zr = (char*)alloc(zeroBytes);
    float* statS = (float*)zr;
    float* statQ = statS + 544;
    float* nodeS = statQ + 544;
    float* nodeQ = nodeS + 128;
    int* cnt    = (int*)(nodeQ + 128);
    int* cursor = cnt + N;
    int* cnt0   = cursor + N;
    int* cnt1   = cnt0 + N;

    int*   indptr = (int*)alloc((size_t)(N + 1) * 4);
    int*   part   = (int*)alloc((size_t)(NB_SCAN + 1) * 4);
    float* dinv   = (float*)alloc((size_t)N * 4);
    int*   csrS   = (int*)alloc((size_t)E * 4);
    float* sNode  = (float*)alloc(128 * 4);
    float* tNode  = (float*)alloc(128 * 4);
    float* sEdge  = (float*)alloc(544 * 4);
    float* tEdge  = (float*)alloc(544 * 4);
    float* b0p    = (float*)alloc(512 * 4);
    u16* Wlinb  = (u16*)alloc((size_t)128 * 128 * 2);
    u16* tagWsPb= (u16*)alloc((size_t)3 * 128 * 256 * 2);  // stacked pairs
    u16* tagW6b = (u16*)alloc((size_t)128 * 128 * 2);      // hop 6
    u16* nlW0b  = (u16*)alloc((size_t)256 * 256 * 2);
    u16* nlW1b  = (u16*)alloc((size_t)128 * 256 * 2);
    u16* clWb   = (u16*)alloc((size_t)128 * 128 * 2);
    u16* elW1b  = (u16*)alloc((size_t)256 * 512 * 2);
    u16* W0pb   = (u16*)alloc((size_t)512 * 544 * 2);
    u16*   hA   = (u16*)alloc((size_t)N * 128 * 2);   // h ping / aEmb
    u16*   hB   = (u16*)alloc((size_t)N * 128 * 2);   // h pong / houtb / Xb
    float* outT = (float*)alloc((size_t)N * 128 * 4); // TAG acc / a256+clbuf / o1

    if (ws_size < off) return;

    u16*   aEmb  = hA;
    u16*   houtb = hB;
    float* out_nodes = (float*)d_out;
    float* out_epred = (float*)d_out + (size_t)N * 8;

    hipMemsetAsync(zr, 0, zeroBytes, stream);

    convTB<<<(128*128 + 255)/256, 256, 0, stream>>>(Wlin, Wlinb, 128, 128, 1);
    conv_pair<<<(3*128*256 + 255)/256, 256, 0, stream>>>(tagWs, tagWsPb);
    convTB<<<(128*128 + 255)/256, 256, 0, stream>>>(tagWs + (size_t)KHOPS*128*128, tagW6b, 128, 128, 1);
    convTB<<<(256*256 + 255)/256, 256, 0, stream>>>(nlW0, nlW0b, 256, 256, 1);
    convTB<<<(256*128 + 255)/256, 256, 0, stream>>>(nlW1, nlW1b, 256, 128, 1);
    convTB<<<(128*128 + 255)/256, 256, 0, stream>>>(clW, clWb, 128, 128, 1);
    convTB<<<(512*256 + 255)/256, 256, 0, stream>>>(elW1, elW1b, 512, 256, 1);

    col_stats<0><<<1024, 256, 0, stream>>>(X, N, 7, nullptr, nullptr, nodeS, nodeQ, 0, 0);
    bn_finalize<<<1, 128, 0, stream>>>(nodeS, nodeQ, bnG, bnB, sNode, tNode, 128, (float)N, 1e-5f);

    dim3 g1((N + 127) / 128, 1);
    gemm_mfma<3, 1, 0, 1><<<g1, 256, 0, stream>>>(X, nullptr, nullptr, nullptr, nullptr, 0,
                                                  sNode, tNode, Wlinb, blin, hA, nullptr, N, 128, 128, 128);

    hist_add<<<2048, 256, 0, stream>>>(EI + E, E, cnt);
    hist_add2<<<1024, 256, 0, stream>>>(I0, I1, P, cnt0, cnt1);
    scan1<<<NB_SCAN, 1024, 0, stream>>>(cnt, indptr, part, N);
    scan2<<<1, 256, 0, stream>>>(part, NB_SCAN);
    scan3<<<NB_SCAN, 1024, 0, stream>>>(indptr, part, cnt, dinv, N);
    csr_build<<<2048, 256, 0, stream>>>(EI, EI + E, E, indptr, cursor, csrS);

    // ---- TAGConv: 3 paired K=256 GEMMs + fused final hop ----
    int spmmGrid = (N * 64 + 255) / 256;
    spmm_hop<<<spmmGrid, 256, 0, stream>>>(hA, hB, indptr, csrS, dinv);          // h1
    gemm_mfma<5, 0, 0, 0><<<g1, 256, 0, stream>>>(hA, hB, nullptr, nullptr, nullptr, 0,
                                                  nullptr, nullptr, tagWsPb, nullptr, outT, nullptr,
                                                  N, 256, 128, 0);
    spmm_hop<<<spmmGrid, 256, 0, stream>>>(hB, hA, indptr, csrS, dinv);          // h2
    spmm_hop<<<spmmGrid, 256, 0, stream>>>(hA, hB, indptr, csrS, dinv);          // h3
    gemm_mfma<5, 0, 1, 0><<<g1, 256, 0, stream>>>(hA, hB, nullptr, nullptr, nullptr, 0,
                                                  nullptr, nullptr, tagWsPb + (size_t)1*128*256,
                                                  nullptr, outT, outT, N, 256, 128, 0);
    spmm_hop<<<spmmGrid, 256, 0, stream>>>(hB, hA, indptr, csrS, dinv);          // h4
    spmm_hop<<<spmmGrid, 256, 0, stream>>>(hA, hB, indptr, csrS, dinv);          // h5
    gemm_mfma<5, 0, 1, 0><<<g1, 256, 0, stream>>>(hA, hB, nullptr, nullptr, nullptr, 0,
                                                  nullptr, nullptr, tagWsPb + (size_t)2*128*256,
                                                  nullptr, outT, outT, N, 256, 128, 0);
    spmm_hop<<<spmmGrid, 256, 0, stream>>>(hB, hA, indptr, csrS, dinv);          // h6
    gemm_mfma<0, 1, 1, 1><<<g1, 256, 0, stream>>>(hA, nullptr, nullptr, nullptr, nullptr, 0,
                                                  nullptr, nullptr, tagW6b, tagB, houtb, outT,
                                                  N, 128, 128, 128);

    // ---- node MLP ----
    u16*   a256  = (u16*)outT;
    float* clbuf = outT;
    {
        dim3 gA((N + 127) / 128, 1);
        gemm_wide<1, 1, 1><<<gA, 512, 0, stream>>>(X, houtb, nullptr, nullptr, nullptr, 0,
                                                   sNode, tNode, nlW0b, nlb0, a256, N, 256, 256);
        dim3 gB((N + 127) / 128, 1);
        gemm_mfma<0, 1, 0, 1><<<gB, 256, 0, stream>>>(a256, nullptr, nullptr, nullptr, nullptr, 0,
                                                      nullptr, nullptr, nlW1b, nlb1, aEmb, nullptr,
                                                      N, 256, 128, 256);
        gemm_mfma<0, 1, 0, 0><<<gB, 256, 0, stream>>>(aEmb, nullptr, nullptr, nullptr, nullptr, 0,
                                                      nullptr, nullptr, clWb, clb, clbuf, nullptr,
                                                      N, 128, 128, 128);
        node_head<<<(N + 3) / 4, 256, 0, stream>>>(clbuf, endW, endB, out_nodes, N);
    }

    // Xb = bf16(X) into hB (houtb dead after node MLP)
    u16* Xb = hB;
    convB<<<2048, 256, 0, stream>>>(X, Xb, N * 128 / 4);

    col_stats<1><<<1024, 256, 0, stream>>>(aEmb, N, 7, cnt0, cnt1, statS, statQ, 0, 128);
    col_stats<1><<<1024, 256, 0, stream>>>(Xb,   N, 7, cnt0, cnt1, statS, statQ, 256, 384);
    col_stats<0><<<1024, 256, 0, stream>>>(Y,    P, 5, nullptr, nullptr, statS, statQ, 512, 0);
    bn_finalize<<<3, 256, 0, stream>>>(statS, statQ, beG, beB, sEdge, tEdge, 544, (float)P, 1.0f);
    fold_wT<<<(512*544 + 255)/256, 256, 0, stream>>>(elW0, sEdge, W0pb);
    fold_b<<<2, 256, 0, stream>>>(elW0, elb0, tEdge, b0p);

    // ---- edge MLP: L1 with 128x256 tiles (grid.y=2), then fused L2+head ----
    u16* o1 = (u16*)outT;
    for (int pb = 0; pb < P; pb += ECHK) {
        int m = (P - pb < ECHK) ? (P - pb) : ECHK;
        dim3 gA((m + 127) / 128, 2);
        gemm_wide<2, 1, 1><<<gA, 512, 0, stream>>>(aEmb, Xb, Y, I0, I1, pb,
                                                   nullptr, nullptr, W0pb, b0p, o1, m, 544, 512);
        dim3 gB((m + 127) / 128, 1);
        gemm_head<<<gB, 512, 0, stream>>>(o1, elW1b, elb1, elEW, elEb, out_epred, pb, m);
    }
}